// Round 5
// baseline (1884.778 us; speedup 1.0000x reference)
//
#include <hip/hip_runtime.h>
#include <math.h>
#include <stdint.h>

#define Bz 64
#define Tz 32
#define Ez 64
#define Hz 256
#define Vz 32000
#define KTOT 320
#define KPADL 260         // logits hLDS row stride (floats)

typedef unsigned long long u64;
typedef unsigned int u32;

__device__ __forceinline__ u32 map_f32(float f) {
  u32 u = __float_as_uint(f);
  return (u & 0x80000000u) ? ~u : (u | 0x80000000u);
}

__device__ __forceinline__ float2 ntf2(const float* p) {
  u64 v = __builtin_nontemporal_load((const u64*)p);
  float2 r;
  r.x = __uint_as_float((u32)v);
  r.y = __uint_as_float((u32)(v >> 32));
  return r;
}

// ---------------- weight repack: P4[j][k][g] (g = i,f,o,c); zero key bufs ----------------
__global__ void k_prep(const float* __restrict__ Wi, const float* __restrict__ Ui,
                       const float* __restrict__ Wf, const float* __restrict__ Uf,
                       const float* __restrict__ Wog, const float* __restrict__ Uog,
                       const float* __restrict__ Wc, const float* __restrict__ Uc,
                       float* __restrict__ P4, u64* __restrict__ key) {
  int j = blockIdx.x;        // 0..255
  int k = threadIdx.x;       // 0..319
  float g0, g1, g2, g3;
  if (k < Ez) {
    g0 = Wi[k*Hz + j]; g1 = Wf[k*Hz + j]; g2 = Wog[k*Hz + j]; g3 = Wc[k*Hz + j];
  } else {
    int kk = k - Ez;
    g0 = Ui[kk*Hz + j]; g1 = Uf[kk*Hz + j]; g2 = Uog[kk*Hz + j]; g3 = Uc[kk*Hz + j];
  }
  float* p = P4 + ((size_t)j*KTOT + k)*4;
  p[0] = g0; p[1] = g1; p[2] = g2; p[3] = g3;
  if (j == 0 && k < 2*Bz) key[k] = 0ull;
}

// ---------------- per-step LSTM cell: 32 blocks x 512 thr; wave = one j, lane = b --------
// x/h staged transposed [k][b] in LDS; weights via wave-uniform scalar stream.
__global__ __launch_bounds__(512) void k_gates(
    int t, const int* __restrict__ gnp,
    const int* __restrict__ input_x, const int* __restrict__ start_tok,
    const float* __restrict__ emb, const float* __restrict__ P4,
    const float* __restrict__ bi_, const float* __restrict__ bf_,
    const float* __restrict__ bog_, const float* __restrict__ bc_,
    const float* __restrict__ hT_in, float* __restrict__ hT_out,
    float* __restrict__ cT,
    const u64* __restrict__ key_prev, u64* __restrict__ key_cur,
    int* __restrict__ out) {
  extern __shared__ float xh[];          // [320][64] transposed, 80 KB
  __shared__ int tok_s[Bz];
  int tid = threadIdx.x;
  int blk = blockIdx.x;
  int gn = *gnp;

  // ---- phase 1: token select (lane b = tid<64) ----
  if (tid < Bz) {
    int b = tid, tk;
    if (t == 0)          tk = start_tok[b];
    else if (t - 1 < gn) tk = input_x[b*Tz + (t-1)];
    else                 tk = (int)(~(u32)(key_prev[b] & 0xFFFFFFFFull));
    tok_s[b] = tk;
    if (blk == 0 && t > 0) out[b*Tz + (t-1)] = tk;
  }
  if (blk == 0 && tid >= 64 && tid < 64 + Bz) key_cur[tid - 64] = 0ull;
  __syncthreads();

  // ---- phase 2: stage x (emb) and h into transposed LDS ----
  {
    int b = tid & 63, part = tid >> 6;           // part 0..7 -> k = part*8..+7
    const float4* e4 = (const float4*)(emb + (size_t)tok_s[b]*Ez + part*8);
    float4 v0 = e4[0], v1 = e4[1];
    int k0 = part*8;
    xh[(k0+0)*Bz + b] = v0.x; xh[(k0+1)*Bz + b] = v0.y;
    xh[(k0+2)*Bz + b] = v0.z; xh[(k0+3)*Bz + b] = v0.w;
    xh[(k0+4)*Bz + b] = v1.x; xh[(k0+5)*Bz + b] = v1.y;
    xh[(k0+6)*Bz + b] = v1.z; xh[(k0+7)*Bz + b] = v1.w;
  }
  if (t > 0) {
    const float4* s4 = (const float4*)hT_in;     // hT layout [j][b] == xh[64+j][b]
    float4* d4 = (float4*)(xh + Ez*Bz);
    #pragma unroll
    for (int i = 0; i < 8; ++i) d4[tid + i*512] = s4[tid + i*512];
  }
  __syncthreads();

  // ---- phase 3: per-lane 4-gate dot; j wave-uniform -> scalar weight loads ----
  int lane = tid & 63;
  int j = __builtin_amdgcn_readfirstlane(blk*8 + (tid >> 6));
  const float* wj = P4 + (size_t)j*KTOT*4;
  float ai = bi_[j], af = bf_[j], ao = bog_[j], ac = bc_[j];

#define GQUAD(k0_) { \
    _Pragma("unroll") \
    for (int kk = 0; kk < 4; ++kk) { \
      float4 wv = *(const float4*)(wj + ((k0_)+kk)*4); \
      float xv = xh[((k0_)+kk)*Bz + lane]; \
      ai = fmaf(xv, wv.x, ai); af = fmaf(xv, wv.y, af); \
      ao = fmaf(xv, wv.z, ao); ac = fmaf(xv, wv.w, ac); } }

  #pragma unroll
  for (int k = 0; k < Ez; k += 4) GQUAD(k)
  if (t > 0) {
    #pragma unroll 8
    for (int k = Ez; k < KTOT; k += 4) GQUAD(k)
  }
#undef GQUAD

  float gi = 1.f/(1.f + expf(-ai));
  float gf = 1.f/(1.f + expf(-af));
  float go = 1.f/(1.f + expf(-ao));
  float gc = tanhf(ac);
  float cold = (t > 0) ? cT[j*Bz + lane] : 0.f;
  float cn = gf*cold + gi*gc;
  float hn = go * tanhf(cn);
  cT[j*Bz + lane]     = cn;
  hT_out[j*Bz + lane] = hn;
}

// ---------------- logits: 504 blocks x 256 thr; block = 8 rows x 512 cols ----------------
// Waves partition columns (unique Wo lines per miss); h broadcast from 8KB LDS.
__global__ __launch_bounds__(256, 2) void k_logits(
    int t, const int* __restrict__ gnp,
    const float* __restrict__ hT,        // [j][b] transposed
    const float* __restrict__ Wo, const float* __restrict__ bo,
    u64* __restrict__ key_cur) {
  int gn = *gnp;
  if (t < gn) return;                    // uniform early-exit (teacher step)
  __shared__ float hLDS[8*KPADL];
  int tid = threadIdx.x;
  int rt = blockIdx.x & 7, p = blockIdx.x >> 3;   // rowgroup, coltile 0..62
  int rbase = rt*8;

  // stage h rows rbase..rbase+7 transposed -> hLDS[r][k]
  {
    const float* src = hT + tid*Bz + rbase;       // tid = k
    float4 a = *(const float4*)(src);
    float4 b = *(const float4*)(src + 4);
    hLDS[0*KPADL + tid] = a.x; hLDS[1*KPADL + tid] = a.y;
    hLDS[2*KPADL + tid] = a.z; hLDS[3*KPADL + tid] = a.w;
    hLDS[4*KPADL + tid] = b.x; hLDS[5*KPADL + tid] = b.y;
    hLDS[6*KPADL + tid] = b.z; hLDS[7*KPADL + tid] = b.w;
  }
  __syncthreads();

  int w = tid >> 6, lane = tid & 63;
  int c = p*512 + w*128 + lane*2;
  if (c >= Vz) return;                   // waves 2,3 of tile 62 (after barrier)

  const float* wbase = Wo + c;
  float2 acc[8];
  {
    float2 b2 = *(const float2*)(bo + c);
    #pragma unroll
    for (int r = 0; r < 8; ++r) acc[r] = b2;
  }

#define WLOAD(W, kk) { const float* _p = wbase + (size_t)(kk)*Vz; \
    W[0] = ntf2(_p); W[1] = ntf2(_p + Vz); W[2] = ntf2(_p + 2*(size_t)Vz); W[3] = ntf2(_p + 3*(size_t)Vz); }
#define HLOAD(H, kk) { _Pragma("unroll") \
    for (int r = 0; r < 8; ++r) H[r] = *(const float4*)(hLDS + r*KPADL + (kk)); }
#define FMAQ(H, W) { _Pragma("unroll") \
    for (int kk = 0; kk < 4; ++kk) { \
      float wx = ((const float*)&W[kk])[0], wy = ((const float*)&W[kk])[1]; \
      _Pragma("unroll") \
      for (int r = 0; r < 8; ++r) { \
        float a = ((const float*)&H[r])[kk]; \
        acc[r].x = fmaf(a, wx, acc[r].x); acc[r].y = fmaf(a, wy, acc[r].y); } } }

  float2 wA[4], wB[4], wC[4], wD[4];
  float4 hA[8], hB[8];
  WLOAD(wA, 0); WLOAD(wB, 4);
  for (int k0 = 0; k0 < Hz; k0 += 8) {
    int kp = (k0 + 8) & (Hz - 1);        // wrap-around prefetch (harmless)
    WLOAD(wC, kp);
    HLOAD(hA, k0);
    FMAQ(hA, wA);
    WLOAD(wD, kp + 4);
    HLOAD(hB, k0 + 4);
    FMAQ(hB, wB);
    #pragma unroll
    for (int q = 0; q < 4; ++q) { wA[q] = wC[q]; wB[q] = wD[q]; }
  }
#undef WLOAD
#undef HLOAD
#undef FMAQ

  // per-row argmax: 2 local cols, then full-wave shuffle reduce (cols span the wave)
  #pragma unroll
  for (int r = 0; r < 8; ++r) {
    float bv = acc[r].x; int bix = c;
    if (acc[r].y > bv) { bv = acc[r].y; bix = c + 1; }
    #pragma unroll
    for (int m = 32; m > 0; m >>= 1) {
      float ov = __shfl_xor(bv, m, 64);
      int   oi = __shfl_xor(bix, m, 64);
      if (ov > bv || (ov == bv && oi < bix)) { bv = ov; bix = oi; }
    }
    if (lane == 0) {
      u64 kv = ((u64)map_f32(bv) << 32) | (u32)(~(u32)bix);
      atomicMax(&key_cur[rbase + r], kv);
    }
  }
}

// ---------------- final token (step T-1) -------------------------------------------------
__global__ void k_final(const int* __restrict__ gnp, const int* __restrict__ input_x,
                        const u64* __restrict__ key_last, int* __restrict__ out) {
  int b = threadIdx.x;
  int gn = *gnp;
  int tk;
  if (Tz - 1 < gn) tk = input_x[b*Tz + Tz - 1];
  else             tk = (int)(~(u32)(key_last[b] & 0xFFFFFFFFull));
  out[b*Tz + Tz - 1] = tk;
}

extern "C" void kernel_launch(void* const* d_in, const int* in_sizes, int n_in,
                              void* d_out, int out_size, void* d_ws, size_t ws_size,
                              hipStream_t stream) {
  const int*   input_x   = (const int*)d_in[0];
  const int*   gnp       = (const int*)d_in[1];
  const int*   start_tok = (const int*)d_in[2];
  const float* emb = (const float*)d_in[3];
  const float* Wi  = (const float*)d_in[4];
  const float* Ui  = (const float*)d_in[5];
  const float* bi  = (const float*)d_in[6];
  const float* Wf  = (const float*)d_in[7];
  const float* Uf  = (const float*)d_in[8];
  const float* bff = (const float*)d_in[9];
  const float* Wog = (const float*)d_in[10];
  const float* Uog = (const float*)d_in[11];
  const float* bog = (const float*)d_in[12];
  const float* Wc  = (const float*)d_in[13];
  const float* Uc  = (const float*)d_in[14];
  const float* bc  = (const float*)d_in[15];
  const float* Wo  = (const float*)d_in[16];
  const float* bo  = (const float*)d_in[17];
  int* out = (int*)d_out;

  float* wsf = (float*)d_ws;
  float* hTA = wsf;                      // 16384 f
  float* hTB = wsf + 16384;              // 16384 f
  float* cT  = wsf + 32768;              // 16384 f
  u64*   key = (u64*)(wsf + 49152);      // 128 u64 = 256 f
  float* P4  = wsf + 49152 + 256;        // 327680 f

  size_t gsm = (size_t)KTOT * Bz * 4;    // 81920 B
  hipFuncSetAttribute((const void*)k_gates,
                      hipFuncAttributeMaxDynamicSharedMemorySize, (int)gsm);

  k_prep<<<dim3(256), dim3(320), 0, stream>>>(Wi, Ui, Wf, Uf, Wog, Uog, Wc, Uc, P4, key);

  for (int t = 0; t < Tz; ++t) {
    const float* hT_in  = (t & 1) ? hTA : hTB;
    float*       hT_out = (t & 1) ? hTB : hTA;
    const u64* key_prev = key + ((t + 1) & 1) * Bz;
    u64*       key_cur  = key + (t & 1) * Bz;
    k_gates<<<dim3(32), dim3(512), gsm, stream>>>(
        t, gnp, input_x, start_tok, emb, P4, bi, bff, bog, bc,
        hT_in, hT_out, cT, key_prev, key_cur, out);
    k_logits<<<dim3(504), dim3(256), 0, stream>>>(
        t, gnp, hT_out, Wo, bo, key_cur);
  }
  k_final<<<dim3(1), dim3(64), 0, stream>>>(
      gnp, input_x, key + ((Tz - 1) & 1) * Bz, out);
}

// Round 6
// 1116.833 us; speedup vs baseline: 1.6876x; 1.6876x over previous
//
#include <hip/hip_runtime.h>
#include <math.h>
#include <stdint.h>

#define Bz 64
#define Tz 32
#define Ez 64
#define Hz 256
#define Vz 32000
#define KTOT 320
#define LCOLS 128      // logits cols per block
#define LCHUNK 32      // k rows per staged chunk

typedef unsigned long long u64;
typedef unsigned int u32;

__device__ __forceinline__ u32 map_f32(float f) {
  u32 u = __float_as_uint(f);
  return (u & 0x80000000u) ? ~u : (u | 0x80000000u);
}

__device__ __forceinline__ void gload_lds16(const float* g, float* l) {
  __builtin_amdgcn_global_load_lds(
      (const __attribute__((address_space(1))) void*)g,
      (__attribute__((address_space(3))) void*)l, 16, 0, 0);
}

// ---------------- weight repack: P4[j][k][g] (g = i,f,o,c); zero key bufs ----------------
__global__ void k_prep(const float* __restrict__ Wi, const float* __restrict__ Ui,
                       const float* __restrict__ Wf, const float* __restrict__ Uf,
                       const float* __restrict__ Wog, const float* __restrict__ Uog,
                       const float* __restrict__ Wc, const float* __restrict__ Uc,
                       float* __restrict__ P4, u64* __restrict__ key) {
  int j = blockIdx.x;        // 0..255
  int k = threadIdx.x;       // 0..319
  float g0, g1, g2, g3;
  if (k < Ez) {
    g0 = Wi[k*Hz + j]; g1 = Wf[k*Hz + j]; g2 = Wog[k*Hz + j]; g3 = Wc[k*Hz + j];
  } else {
    int kk = k - Ez;
    g0 = Ui[kk*Hz + j]; g1 = Uf[kk*Hz + j]; g2 = Uog[kk*Hz + j]; g3 = Uc[kk*Hz + j];
  }
  float* p = P4 + ((size_t)j*KTOT + k)*4;
  p[0] = g0; p[1] = g1; p[2] = g2; p[3] = g3;
  if (j == 0 && k < 2*Bz) key[k] = 0ull;
}

// ---------------- per-step LSTM cell: 32 blocks x 512 thr; wave = one j, lane = b --------
__global__ __launch_bounds__(512) void k_gates(
    int t, const int* __restrict__ gnp,
    const int* __restrict__ input_x, const int* __restrict__ start_tok,
    const float* __restrict__ emb, const float* __restrict__ P4,
    const float* __restrict__ bi_, const float* __restrict__ bf_,
    const float* __restrict__ bog_, const float* __restrict__ bc_,
    const float* __restrict__ hT_in, float* __restrict__ hT_out,
    float* __restrict__ cT,
    const u64* __restrict__ key_prev, u64* __restrict__ key_cur,
    int* __restrict__ out) {
  extern __shared__ float xh[];          // [320][64] transposed, 80 KB
  __shared__ int tok_s[Bz];
  int tid = threadIdx.x;
  int blk = blockIdx.x;
  int gn = *gnp;

  if (tid < Bz) {
    int b = tid, tk;
    if (t == 0)          tk = start_tok[b];
    else if (t - 1 < gn) tk = input_x[b*Tz + (t-1)];
    else                 tk = (int)(~(u32)(key_prev[b] & 0xFFFFFFFFull));
    tok_s[b] = tk;
    if (blk == 0 && t > 0) out[b*Tz + (t-1)] = tk;
  }
  if (blk == 0 && tid >= 64 && tid < 64 + Bz) key_cur[tid - 64] = 0ull;
  __syncthreads();

  {
    int b = tid & 63, part = tid >> 6;           // part 0..7 -> k = part*8..+7
    const float4* e4 = (const float4*)(emb + (size_t)tok_s[b]*Ez + part*8);
    float4 v0 = e4[0], v1 = e4[1];
    int k0 = part*8;
    xh[(k0+0)*Bz + b] = v0.x; xh[(k0+1)*Bz + b] = v0.y;
    xh[(k0+2)*Bz + b] = v0.z; xh[(k0+3)*Bz + b] = v0.w;
    xh[(k0+4)*Bz + b] = v1.x; xh[(k0+5)*Bz + b] = v1.y;
    xh[(k0+6)*Bz + b] = v1.z; xh[(k0+7)*Bz + b] = v1.w;
  }
  if (t > 0) {
    const float4* s4 = (const float4*)hT_in;     // hT layout [j][b] == xh[64+j][b]
    float4* d4 = (float4*)(xh + Ez*Bz);
    #pragma unroll
    for (int i = 0; i < 8; ++i) d4[tid + i*512] = s4[tid + i*512];
  }
  __syncthreads();

  int lane = tid & 63;
  int j = __builtin_amdgcn_readfirstlane(blk*8 + (tid >> 6));
  const float* wj = P4 + (size_t)j*KTOT*4;
  float ai = bi_[j], af = bf_[j], ao = bog_[j], ac = bc_[j];

#define GQUAD(k0_) { \
    _Pragma("unroll") \
    for (int kk = 0; kk < 4; ++kk) { \
      float4 wv = *(const float4*)(wj + ((k0_)+kk)*4); \
      float xv = xh[((k0_)+kk)*Bz + lane]; \
      ai = fmaf(xv, wv.x, ai); af = fmaf(xv, wv.y, af); \
      ao = fmaf(xv, wv.z, ao); ac = fmaf(xv, wv.w, ac); } }

  #pragma unroll
  for (int k = 0; k < Ez; k += 4) GQUAD(k)
  if (t > 0) {
    #pragma unroll 8
    for (int k = Ez; k < KTOT; k += 4) GQUAD(k)
  }
#undef GQUAD

  float gi = 1.f/(1.f + expf(-ai));
  float gf = 1.f/(1.f + expf(-af));
  float go = 1.f/(1.f + expf(-ao));
  float gc = tanhf(ac);
  float cold = (t > 0) ? cT[j*Bz + lane] : 0.f;
  float cn = gf*cold + gi*gc;
  float hn = go * tanhf(cn);
  cT[j*Bz + lane]     = cn;
  hT_out[j*Bz + lane] = hn;
}

// ---------------- logits: 250 blocks x 512 thr; block = ALL 64 rows x 128 cols -----------
// One block per col-tile: XCD x (bid%8) owns a disjoint ~4MB Wo slice -> L2-resident.
// Wo staged via async global_load_lds, dbuf K=32 chunks, counted vmcnt + raw s_barrier.
__global__ __launch_bounds__(512, 1) void k_logits(
    int t, const int* __restrict__ gnp,
    const float* __restrict__ hT,        // [k][b]
    const float* __restrict__ Wo, const float* __restrict__ bo,
    u64* __restrict__ key_cur) {
  int gn = *gnp;
  if (t < gn) return;                    // uniform early-exit (teacher step)
  extern __shared__ float sm[];
  float* hLDS = sm;                      // [256][64] = 16384 f (64 KB)
  float* wbuf = sm + 16384;              // 2 x [32][128] = 8192 f (32 KB)

  int tid = threadIdx.x;
  int c0 = blockIdx.x * LCOLS;
  int rg = tid >> 5, cg = tid & 31;      // 16 row-groups x 32 col-groups
  int cc0 = c0 + cg*4;

  float acc[4][4];
  {
    float4 b4 = *(const float4*)(bo + cc0);
    #pragma unroll
    for (int i = 0; i < 4; ++i) { acc[i][0]=b4.x; acc[i][1]=b4.y; acc[i][2]=b4.z; acc[i][3]=b4.w; }
  }

  // stage hT -> hLDS (64 KB, coalesced)
  {
    const float4* s4 = (const float4*)hT;
    float4* d4 = (float4*)hLDS;
    #pragma unroll
    for (int i = 0; i < 8; ++i) d4[tid + i*512] = s4[tid + i*512];
  }
  __syncthreads();                       // full drain once (also fences h stage)

  int w = tid >> 6, lane = tid & 63;
  // STAGE chunk q into parity p: per wave rows w*4..w*4+3, 2 async instrs of 2 rows each
#define STAGE(q_, p_) { \
    const float* gsrc = Wo + ((size_t)((q_)*LCHUNK + w*4 + (lane>>5)))*Vz + c0 + ((lane&31)<<2); \
    float* ldst = wbuf + (p_)*4096 + (w*4)*LCOLS; \
    gload_lds16(gsrc, ldst); \
    gload_lds16(gsrc + 2*(size_t)Vz, ldst + 2*LCOLS); }

#define COMPUTE(q_, p_) { \
    const float* wb = wbuf + (p_)*4096; \
    _Pragma("unroll 4") \
    for (int k = 0; k < LCHUNK; ++k) { \
      float4 hv = *(const float4*)(hLDS + ((q_)*LCHUNK + k)*Bz + rg*4); \
      float4 wv = *(const float4*)(wb + k*LCOLS + cg*4); \
      const float* hp = (const float*)&hv; \
      _Pragma("unroll") \
      for (int i = 0; i < 4; ++i) { \
        float a = hp[i]; \
        acc[i][0] = fmaf(a, wv.x, acc[i][0]); acc[i][1] = fmaf(a, wv.y, acc[i][1]); \
        acc[i][2] = fmaf(a, wv.z, acc[i][2]); acc[i][3] = fmaf(a, wv.w, acc[i][3]); } } }

  STAGE(0, 0)
  #pragma unroll 1
  for (int q = 0; q < 7; ++q) {
    STAGE(q+1, (q+1)&1)
    asm volatile("s_waitcnt vmcnt(2)" ::: "memory");   // chunk q landed (next still in flight)
    __builtin_amdgcn_s_barrier();
    COMPUTE(q, q&1)
    asm volatile("" ::: "memory");
    __builtin_amdgcn_s_barrier();                      // all waves done reading buf before reuse
  }
  asm volatile("s_waitcnt vmcnt(0)" ::: "memory");
  __builtin_amdgcn_s_barrier();
  COMPUTE(7, 1)
#undef STAGE
#undef COMPUTE

  // per-row argmax: 4 local cols, then 32-lane (one rg) shuffle reduce, first-index-wins
  #pragma unroll
  for (int i = 0; i < 4; ++i) {
    float bv = acc[i][0]; int bix = cc0;
    #pragma unroll
    for (int cc = 1; cc < 4; ++cc)
      if (acc[i][cc] > bv) { bv = acc[i][cc]; bix = cc0 + cc; }
    #pragma unroll
    for (int m = 16; m > 0; m >>= 1) {
      float ov = __shfl_xor(bv, m, 32);
      int   oi = __shfl_xor(bix, m, 32);
      if (ov > bv || (ov == bv && oi < bix)) { bv = ov; bix = oi; }
    }
    if (cg == 0) {
      u64 kv = ((u64)map_f32(bv) << 32) | (u32)(~(u32)bix);
      atomicMax(&key_cur[rg*4 + i], kv);
    }
  }
}

// ---------------- final token (step T-1) -------------------------------------------------
__global__ void k_final(const int* __restrict__ gnp, const int* __restrict__ input_x,
                        const u64* __restrict__ key_last, int* __restrict__ out) {
  int b = threadIdx.x;
  int gn = *gnp;
  int tk;
  if (Tz - 1 < gn) tk = input_x[b*Tz + Tz - 1];
  else             tk = (int)(~(u32)(key_last[b] & 0xFFFFFFFFull));
  out[b*Tz + Tz - 1] = tk;
}

extern "C" void kernel_launch(void* const* d_in, const int* in_sizes, int n_in,
                              void* d_out, int out_size, void* d_ws, size_t ws_size,
                              hipStream_t stream) {
  const int*   input_x   = (const int*)d_in[0];
  const int*   gnp       = (const int*)d_in[1];
  const int*   start_tok = (const int*)d_in[2];
  const float* emb = (const float*)d_in[3];
  const float* Wi  = (const float*)d_in[4];
  const float* Ui  = (const float*)d_in[5];
  const float* bi  = (const float*)d_in[6];
  const float* Wf  = (const float*)d_in[7];
  const float* Uf  = (const float*)d_in[8];
  const float* bff = (const float*)d_in[9];
  const float* Wog = (const float*)d_in[10];
  const float* Uog = (const float*)d_in[11];
  const float* bog = (const float*)d_in[12];
  const float* Wc  = (const float*)d_in[13];
  const float* Uc  = (const float*)d_in[14];
  const float* bc  = (const float*)d_in[15];
  const float* Wo  = (const float*)d_in[16];
  const float* bo  = (const float*)d_in[17];
  int* out = (int*)d_out;

  float* wsf = (float*)d_ws;
  float* hTA = wsf;                      // 16384 f
  float* hTB = wsf + 16384;              // 16384 f
  float* cT  = wsf + 32768;              // 16384 f
  u64*   key = (u64*)(wsf + 49152);      // 128 u64 = 256 f
  float* P4  = wsf + 49152 + 256;        // 327680 f

  size_t gsm = (size_t)KTOT * Bz * 4;    // 81920 B
  size_t lsm = (size_t)(16384 + 8192) * 4;  // 98304 B
  hipFuncSetAttribute((const void*)k_gates,
                      hipFuncAttributeMaxDynamicSharedMemorySize, (int)gsm);
  hipFuncSetAttribute((const void*)k_logits,
                      hipFuncAttributeMaxDynamicSharedMemorySize, (int)lsm);

  k_prep<<<dim3(256), dim3(320), 0, stream>>>(Wi, Ui, Wf, Uf, Wog, Uog, Wc, Uc, P4, key);

  for (int t = 0; t < Tz; ++t) {
    const float* hT_in  = (t & 1) ? hTA : hTB;
    float*       hT_out = (t & 1) ? hTB : hTA;
    const u64* key_prev = key + ((t + 1) & 1) * Bz;
    u64*       key_cur  = key + (t & 1) * Bz;
    k_gates<<<dim3(32), dim3(512), gsm, stream>>>(
        t, gnp, input_x, start_tok, emb, P4, bi, bff, bog, bc,
        hT_in, hT_out, cT, key_prev, key_cur, out);
    k_logits<<<dim3(250), dim3(512), lsm, stream>>>(
        t, gnp, hT_out, Wo, bo, key_cur);
  }
  k_final<<<dim3(1), dim3(64), 0, stream>>>(
      gnp, input_x, key + ((Tz - 1) & 1) * Bz, out);
}

// Round 9
// 908.689 us; speedup vs baseline: 2.0742x; 1.2291x over previous
//
#include <hip/hip_runtime.h>
#include <math.h>
#include <stdint.h>

#define Bz 64
#define Tz 32
#define Ez 64
#define Hz 256
#define Vz 32000
#define KTOT 320

typedef unsigned long long u64;
typedef unsigned int u32;

__device__ __forceinline__ u32 map_f32(float f) {
  u32 u = __float_as_uint(f);
  return (u & 0x80000000u) ? ~u : (u | 0x80000000u);
}

__device__ __forceinline__ void gload_lds16(const float* g, float* l) {
  __builtin_amdgcn_global_load_lds(
      (const __attribute__((address_space(1))) void*)g,
      (__attribute__((address_space(3))) void*)l, 16, 0, 0);
}

// ---------------- weight repack: P4[j][k][g] (g = i,f,o,c); zero key bufs ----------------
// (byte-identical to round 6's passing k_prep)
__global__ void k_prep(const float* __restrict__ Wi, const float* __restrict__ Ui,
                       const float* __restrict__ Wf, const float* __restrict__ Uf,
                       const float* __restrict__ Wog, const float* __restrict__ Uog,
                       const float* __restrict__ Wc, const float* __restrict__ Uc,
                       float* __restrict__ P4, u64* __restrict__ key) {
  int j = blockIdx.x;        // 0..255
  int k = threadIdx.x;       // 0..319
  float g0, g1, g2, g3;
  if (k < Ez) {
    g0 = Wi[k*Hz + j]; g1 = Wf[k*Hz + j]; g2 = Wog[k*Hz + j]; g3 = Wc[k*Hz + j];
  } else {
    int kk = k - Ez;
    g0 = Ui[kk*Hz + j]; g1 = Uf[kk*Hz + j]; g2 = Uog[kk*Hz + j]; g3 = Uc[kk*Hz + j];
  }
  float* p = P4 + ((size_t)j*KTOT + k)*4;
  p[0] = g0; p[1] = g1; p[2] = g2; p[3] = g3;
  if (j == 0 && k < 2*Bz) key[k] = 0ull;
}

// ---------------- per-step LSTM cell: 32 blocks x 512 thr; wave = one j, lane = b --------
// (byte-identical to round 6's passing k_gates)
__global__ __launch_bounds__(512) void k_gates(
    int t, const int* __restrict__ gnp,
    const int* __restrict__ input_x, const int* __restrict__ start_tok,
    const float* __restrict__ emb, const float* __restrict__ P4,
    const float* __restrict__ bi_, const float* __restrict__ bf_,
    const float* __restrict__ bog_, const float* __restrict__ bc_,
    const float* __restrict__ hT_in, float* __restrict__ hT_out,
    float* __restrict__ cT,
    const u64* __restrict__ key_prev, u64* __restrict__ key_cur,
    int* __restrict__ out) {
  extern __shared__ float xh[];          // [320][64] transposed, 80 KB
  __shared__ int tok_s[Bz];
  int tid = threadIdx.x;
  int blk = blockIdx.x;
  int gn = *gnp;

  if (tid < Bz) {
    int b = tid, tk;
    if (t == 0)          tk = start_tok[b];
    else if (t - 1 < gn) tk = input_x[b*Tz + (t-1)];
    else                 tk = (int)(~(u32)(key_prev[b] & 0xFFFFFFFFull));
    tok_s[b] = tk;
    if (blk == 0 && t > 0) out[b*Tz + (t-1)] = tk;
  }
  if (blk == 0 && tid >= 64 && tid < 64 + Bz) key_cur[tid - 64] = 0ull;
  __syncthreads();

  {
    int b = tid & 63, part = tid >> 6;           // part 0..7 -> k = part*8..+7
    const float4* e4 = (const float4*)(emb + (size_t)tok_s[b]*Ez + part*8);
    float4 v0 = e4[0], v1 = e4[1];
    int k0 = part*8;
    xh[(k0+0)*Bz + b] = v0.x; xh[(k0+1)*Bz + b] = v0.y;
    xh[(k0+2)*Bz + b] = v0.z; xh[(k0+3)*Bz + b] = v0.w;
    xh[(k0+4)*Bz + b] = v1.x; xh[(k0+5)*Bz + b] = v1.y;
    xh[(k0+6)*Bz + b] = v1.z; xh[(k0+7)*Bz + b] = v1.w;
  }
  if (t > 0) {
    const float4* s4 = (const float4*)hT_in;     // hT layout [j][b] == xh[64+j][b]
    float4* d4 = (float4*)(xh + Ez*Bz);
    #pragma unroll
    for (int i = 0; i < 8; ++i) d4[tid + i*512] = s4[tid + i*512];
  }
  __syncthreads();

  int lane = tid & 63;
  int j = __builtin_amdgcn_readfirstlane(blk*8 + (tid >> 6));
  const float* wj = P4 + (size_t)j*KTOT*4;
  float ai = bi_[j], af = bf_[j], ao = bog_[j], ac = bc_[j];

#define GQUAD(k0_) { \
    _Pragma("unroll") \
    for (int kk = 0; kk < 4; ++kk) { \
      float4 wv = *(const float4*)(wj + ((k0_)+kk)*4); \
      float xv = xh[((k0_)+kk)*Bz + lane]; \
      ai = fmaf(xv, wv.x, ai); af = fmaf(xv, wv.y, af); \
      ao = fmaf(xv, wv.z, ao); ac = fmaf(xv, wv.w, ac); } }

  #pragma unroll
  for (int k = 0; k < Ez; k += 4) GQUAD(k)
  if (t > 0) {
    #pragma unroll 8
    for (int k = Ez; k < KTOT; k += 4) GQUAD(k)
  }
#undef GQUAD

  float gi = 1.f/(1.f + expf(-ai));
  float gf = 1.f/(1.f + expf(-af));
  float go = 1.f/(1.f + expf(-ao));
  float gc = tanhf(ac);
  float cold = (t > 0) ? cT[j*Bz + lane] : 0.f;
  float cn = gf*cold + gi*gc;
  float hn = go * tanhf(cn);
  cT[j*Bz + lane]     = cn;
  hT_out[j*Bz + lane] = hn;
}

// ---------------- logits: 250 blocks x 512 thr; barrier-free per-wave k-pipelines --------
// wave = (seg = wid>>1 -> k in [seg*64, seg*64+64), chalf = wid&1 -> 64 cols)
// lane = (rg = lane>>3 -> 8 rows, cg = lane&7 -> 8 cols); acc[8][8] in registers.
__global__ __launch_bounds__(512, 1) void k_logits(
    int t, const int* __restrict__ gnp,
    const float* __restrict__ hT,        // [k][b]
    const float* __restrict__ Wo, const float* __restrict__ bo,
    u64* __restrict__ key_cur) {         // 64 slots (round-6 layout)
  int gn = *gnp;
  if (t < gn) return;                    // uniform early-exit (teacher step)
  extern __shared__ float sm[];
  float* hLDS = sm;                      // 16384 f (64 KB)
  float* wbuf = sm + 16384;              // 16384 f (64 KB): 8 waves x 2 x 1024

  int tid = threadIdx.x;
  int bid = blockIdx.x;
  int wid = tid >> 6, lane = tid & 63;
  int seg = wid >> 1, chalf = wid & 1;
  int rg = lane >> 3, cg = lane & 7;

  float bo8[8];
  {
    const float4* b4 = (const float4*)(bo + bid*128 + chalf*64 + cg*8);
    float4 x = b4[0], y = b4[1];
    bo8[0]=x.x; bo8[1]=x.y; bo8[2]=x.z; bo8[3]=x.w;
    bo8[4]=y.x; bo8[5]=y.y; bo8[6]=y.z; bo8[7]=y.w;
  }
  // stage hT -> hLDS (coalesced)
  {
    const float4* s4 = (const float4*)hT;
    float4* d4 = (float4*)hLDS;
    #pragma unroll
    for (int i = 0; i < 8; ++i) d4[tid + i*512] = s4[tid + i*512];
  }
  __syncthreads();

  float acc[8][8] = {};
  float* wb = wbuf + wid*2048;
  const float* gW = Wo + bid*128;

#define STAGE(q_, p_) { \
    int kb = seg*64 + (q_)*8; \
    _Pragma("unroll") \
    for (int i = 0; i < 4; ++i) { \
      int row = kb + i*2 + (lane>>5); \
      gload_lds16(gW + (size_t)row*Vz + ((lane&31)<<2), wb + (p_)*1024 + i*256); \
    } }

// FIX vs round 7/8: the W-fragment read must include this wave's column half
// (chalf*64). Without it both column-half waves computed cols 0..63 and the
// chalf=1 wave attached indices 64..127 to those values -> absmax 31707.
#define COMPUTE(q_, p_) { \
    const float* wp = wb + (p_)*1024; \
    const float* hp = hLDS + (seg*64 + (q_)*8)*Bz + rg*8; \
    _Pragma("unroll") \
    for (int kk = 0; kk < 8; ++kk) { \
      float4 h0 = *(const float4*)(hp + kk*Bz); \
      float4 h1 = *(const float4*)(hp + kk*Bz + 4); \
      float4 w0 = *(const float4*)(wp + kk*128 + chalf*64 + cg*8); \
      float4 w1 = *(const float4*)(wp + kk*128 + chalf*64 + cg*8 + 4); \
      float hv[8] = {h0.x,h0.y,h0.z,h0.w,h1.x,h1.y,h1.z,h1.w}; \
      float wv[8] = {w0.x,w0.y,w0.z,w0.w,w1.x,w1.y,w1.z,w1.w}; \
      _Pragma("unroll") \
      for (int r = 0; r < 8; ++r) { \
        _Pragma("unroll") \
        for (int c = 0; c < 8; ++c) acc[r][c] = fmaf(hv[r], wv[c], acc[r][c]); } \
    } }

  STAGE(0, 0)
  #pragma unroll 1
  for (int q = 0; q < 7; ++q) {
    STAGE(q+1, (q+1)&1)
    asm volatile("s_waitcnt vmcnt(4)" ::: "memory");   // oldest chunk landed; newest in flight
    __builtin_amdgcn_sched_barrier(0);
    COMPUTE(q, q&1)
  }
  asm volatile("s_waitcnt vmcnt(0)" ::: "memory");
  __builtin_amdgcn_sched_barrier(0);
  COMPUTE(7, 1)
#undef STAGE
#undef COMPUTE

  // ---- merge k-segment partials: (seg2,seg3) -> (seg0,seg1), then seg1 -> seg0 ----
  float* scratch = wbuf;                 // 4 regions x 4096 f
  __syncthreads();                       // all waves done with private wbuf
  if (wid >= 4) {
    float* r = scratch + (wid-4)*4096;
    #pragma unroll
    for (int i = 0; i < 64; ++i) r[i*64 + lane] = acc[i>>3][i&7];
  }
  __syncthreads();
  if (wid < 4) {
    const float* r = scratch + wid*4096;
    #pragma unroll
    for (int i = 0; i < 64; ++i) acc[i>>3][i&7] += r[i*64 + lane];
  }
  __syncthreads();
  if (wid == 2 || wid == 3) {
    float* r = scratch + (wid-2)*4096;
    #pragma unroll
    for (int i = 0; i < 64; ++i) r[i*64 + lane] = acc[i>>3][i&7];
  }
  __syncthreads();

  if (wid < 2) {
    const float* r = scratch + wid*4096;
    #pragma unroll
    for (int i = 0; i < 64; ++i) acc[i>>3][i&7] += r[i*64 + lane];

    // per-row argmax over this wave's 64 cols; first-index-wins
    int cbase = bid*128 + chalf*64 + cg*8;
    float myv = 0.f; int myi = 0;
    #pragma unroll
    for (int rr = 0; rr < 8; ++rr) {
      float bv = acc[rr][0] + bo8[0]; int bix = cbase;
      #pragma unroll
      for (int c = 1; c < 8; ++c) {
        float v = acc[rr][c] + bo8[c];
        if (v > bv) { bv = v; bix = cbase + c; }
      }
      #pragma unroll
      for (int m = 1; m < 8; m <<= 1) {
        float ov = __shfl_xor(bv, m, 64);
        int   oi = __shfl_xor(bix, m, 64);
        if (ov > bv || (ov == bv && oi < bix)) { bv = ov; bix = oi; }
      }
      if (cg == rr) { myv = bv; myi = bix; }
    }
    int row = rg*8 + cg;
    u64 kv = ((u64)map_f32(myv) << 32) | (u32)(~(u32)myi);
    atomicMax(&key_cur[row], kv);
  }
}

// ---------------- final token (step T-1) -------------------------------------------------
// (byte-identical to round 6's passing k_final)
__global__ void k_final(const int* __restrict__ gnp, const int* __restrict__ input_x,
                        const u64* __restrict__ key_last, int* __restrict__ out) {
  int b = threadIdx.x;
  int gn = *gnp;
  int tk;
  if (Tz - 1 < gn) tk = input_x[b*Tz + Tz - 1];
  else             tk = (int)(~(u32)(key_last[b] & 0xFFFFFFFFull));
  out[b*Tz + Tz - 1] = tk;
}

extern "C" void kernel_launch(void* const* d_in, const int* in_sizes, int n_in,
                              void* d_out, int out_size, void* d_ws, size_t ws_size,
                              hipStream_t stream) {
  const int*   input_x   = (const int*)d_in[0];
  const int*   gnp       = (const int*)d_in[1];
  const int*   start_tok = (const int*)d_in[2];
  const float* emb = (const float*)d_in[3];
  const float* Wi  = (const float*)d_in[4];
  const float* Ui  = (const float*)d_in[5];
  const float* bi  = (const float*)d_in[6];
  const float* Wf  = (const float*)d_in[7];
  const float* Uf  = (const float*)d_in[8];
  const float* bff = (const float*)d_in[9];
  const float* Wog = (const float*)d_in[10];
  const float* Uog = (const float*)d_in[11];
  const float* bog = (const float*)d_in[12];
  const float* Wc  = (const float*)d_in[13];
  const float* Uc  = (const float*)d_in[14];
  const float* bc  = (const float*)d_in[15];
  const float* Wo  = (const float*)d_in[16];
  const float* bo  = (const float*)d_in[17];
  int* out = (int*)d_out;

  float* wsf = (float*)d_ws;
  float* hTA = wsf;                      // 16384 f
  float* hTB = wsf + 16384;              // 16384 f
  float* cT  = wsf + 32768;              // 16384 f
  u64*   key = (u64*)(wsf + 49152);      // 128 u64 = 256 f
  float* P4  = wsf + 49152 + 256;        // 327680 f

  size_t gsm = (size_t)KTOT * Bz * 4;    // 81920 B
  size_t lsm = (size_t)(16384 + 16384) * 4;  // 131072 B
  hipFuncSetAttribute((const void*)k_gates,
                      hipFuncAttributeMaxDynamicSharedMemorySize, (int)gsm);
  hipFuncSetAttribute((const void*)k_logits,
                      hipFuncAttributeMaxDynamicSharedMemorySize, (int)lsm);

  k_prep<<<dim3(256), dim3(320), 0, stream>>>(Wi, Ui, Wf, Uf, Wog, Uog, Wc, Uc, P4, key);

  for (int t = 0; t < Tz; ++t) {
    const float* hT_in  = (t & 1) ? hTA : hTB;
    float*       hT_out = (t & 1) ? hTB : hTA;
    const u64* key_prev = key + ((t + 1) & 1) * Bz;
    u64*       key_cur  = key + (t & 1) * Bz;
    k_gates<<<dim3(32), dim3(512), gsm, stream>>>(
        t, gnp, input_x, start_tok, emb, P4, bi, bff, bog, bc,
        hT_in, hT_out, cT, key_prev, key_cur, out);
    k_logits<<<dim3(250), dim3(512), lsm, stream>>>(
        t, gnp, hT_out, Wo, bo, key_cur);
  }
  k_final<<<dim3(1), dim3(64), 0, stream>>>(
      gnp, input_x, key + ((Tz - 1) & 1) * Bz, out);
}